// Round 21
// baseline (998.896 us; speedup 1.0000x reference)
//
#include <hip/hip_runtime.h>
#include <hip/hip_fp16.h>
#include <stdint.h>

// Problem constants (NamedEntityRecognitionModel)
#define TAGS  32
#define EMB   256
#define HID   512
#define HSZ   256        // per-direction hidden
#define G4H   1024       // 4*HSZ
#define BATCH 64
#define TLEN  512

typedef _Float16 half8  __attribute__((ext_vector_type(8)));
typedef _Float16 half2v __attribute__((ext_vector_type(2)));
typedef float    f32x4  __attribute__((ext_vector_type(4)));
typedef int      i32x4  __attribute__((ext_vector_type(4)));
typedef unsigned int u32x4v __attribute__((ext_vector_type(4)));

#if defined(__has_builtin)
#if __has_builtin(__builtin_amdgcn_fdot2)
#define HAVE_FDOT2 1
#endif
#endif

__device__ __forceinline__ float fdot2f(unsigned a, unsigned b, float c) {
    half2v ha = __builtin_bit_cast(half2v, a);
    half2v hb = __builtin_bit_cast(half2v, b);
#ifdef HAVE_FDOT2
    return __builtin_amdgcn_fdot2(ha, hb, c, false);
#else
    return c + (float)ha[0]*(float)hb[0] + (float)ha[1]*(float)hb[1];
#endif
}
__device__ __forceinline__ float sigmoid_f(float x){ return 1.0f/(1.0f+__expf(-x)); }
__device__ __forceinline__ float tanh_f(float x){ return 1.0f - 2.0f/(__expf(2.0f*x)+1.0f); }

// LDS-only barrier (R14-verified equal to __syncthreads here).
__device__ __forceinline__ void ldsbar() {
    asm volatile("s_waitcnt lgkmcnt(0)" ::: "memory");
    __builtin_amdgcn_sched_barrier(0);
    __builtin_amdgcn_s_barrier();
    __builtin_amdgcn_sched_barrier(0);
}

// ---------------------------------------------------------------------------
// K0: fused prep — Wh int8 image (ids 0..32767) + Wi f16 image (rest).
// grid 384 x 256.
// ---------------------------------------------------------------------------
__global__ __launch_bounds__(256)
void prep_kernel(const float* __restrict__ WhF, const float* __restrict__ WhB,
                 u32x4v* __restrict__ WhI8,
                 const float* __restrict__ WiF, const float* __restrict__ WiB,
                 half8* __restrict__ WiT) {
    const int id = blockIdx.x * 256 + threadIdx.x;   // 0..98303
    if (id < 32768) {
        const int dir = id >> 14, r = id & 16383;
        const int lane = r & 63;
        const int ks = (r >> 6) & 3;
        const int gg = (r >> 8) & 7;
        const int w  = (r >> 11) & 7;
        const int n = (gg >> 1) * 256 + w * 32 + (gg & 1) * 16 + (lane & 15);
        const int k = ks * 64 + (lane >> 4) * 16;
        const float* src = (dir ? WhB : WhF) + (size_t)n * HSZ + k;
        u32x4v out;
#pragma unroll
        for (int d = 0; d < 4; ++d) {
            unsigned dw = 0;
#pragma unroll
            for (int e = 0; e < 4; ++e) {
                int q = __float2int_rn(src[d * 4 + e] * 256.0f);
                q = q > 127 ? 127 : (q < -127 ? -127 : q);
                dw |= ((unsigned)(q & 0xff)) << (8 * e);
            }
            out[d] = dw;
        }
        WhI8[id] = out;
    } else {
        const int slot = id - 32768;                 // 0..65535
        const int lane = slot & 63;
        const int ks = (slot >> 6) & 7;
        const int nt = (slot >> 9) & 63;
        const int dir = slot >> 15;
        const int n = nt * 16 + (lane & 15);
        const int k = ks * 32 + (lane >> 4) * 8;
        const float* src = (dir ? WiB : WiF) + (size_t)n * EMB + k;
        half8 hv;
#pragma unroll
        for (int e = 0; e < 8; ++e) hv[e] = (_Float16)src[e];
        WiT[slot] = hv;
    }
}

// ---------------------------------------------------------------------------
// K1: MFMA input GEMM v4 — v3 layout (wave = 2 m-tiles x 16 nt) but with
// launch_bounds(512,1) (256-VGPR budget: no spill) and DEPTH-2 B prefetch
// (b0/b1/b2 rotation covers ~2 iters ~ L2 latency).
// xWT[dir][b 64][t][n 1024] f16 = embed.Wi + bias. grid (512 t, 2 dir).
// ---------------------------------------------------------------------------
__global__ __launch_bounds__(512, 1)
void gemm_xwt_kernel(const int* __restrict__ X, const float* __restrict__ embed,
                     const half8* __restrict__ WiT, const float* __restrict__ bF,
                     const float* __restrict__ bB, __half* __restrict__ xWT) {
    const int t   = blockIdx.x;
    const int dir = blockIdx.y;
    const int tid = threadIdx.x;
    const int lane = tid & 63;
    const int w    = tid >> 6;        // 0..7
    const int mtp  = (w >> 2) * 2;    // first m-tile of this wave's pair
    const int nq   = w & 3;           // n-quarter (16 nt tiles)
    const int l15  = lane & 15;
    const int lp   = lane >> 4;
    const float* bias = dir ? bB : bF;

    __shared__ ushort A[4 * 8 * 64 * 8];   // [mt][ks][lane][8e] f16 = 32 KB

    // ---- stage A: row b = tid>>3, k-slice ks = tid&7 (32 floats) ----
    {
        const int b = tid >> 3, ks = tid & 7;
        const int erow = X[b * TLEN + t];
        const float* src = embed + (size_t)erow * EMB + ks * 32;
        const int amt = b >> 4, bl = b & 15;
#pragma unroll
        for (int lpp = 0; lpp < 4; ++lpp) {
            const float4 x0 = *(const float4*)(src + lpp * 8);
            const float4 x1 = *(const float4*)(src + lpp * 8 + 4);
            half8 hv;
            hv[0]=(_Float16)x0.x; hv[1]=(_Float16)x0.y; hv[2]=(_Float16)x0.z; hv[3]=(_Float16)x0.w;
            hv[4]=(_Float16)x1.x; hv[5]=(_Float16)x1.y; hv[6]=(_Float16)x1.z; hv[7]=(_Float16)x1.w;
            *(half8*)&A[(((amt * 8 + ks) * 64) + lpp * 16 + bl) * 8] = hv;
        }
    }
    __syncthreads();

    // ---- hoist this wave's A-frags (two m-tiles): 64 VGPR ----
    half8 afr[2][8];
#pragma unroll
    for (int e = 0; e < 2; ++e)
#pragma unroll
        for (int ks = 0; ks < 8; ++ks)
            afr[e][ks] = *(const half8*)&A[((((mtp + e) * 8 + ks) * 64) + lane) * 8];

    const half8* Bw = WiT + (size_t)(dir * 64 + nq * 16) * 8 * 64;

    half8 b0[8], b1[8], b2[8];
#pragma unroll
    for (int ks = 0; ks < 8; ++ks) b0[ks] = Bw[(size_t)ks * 64 + lane];
#pragma unroll
    for (int ks = 0; ks < 8; ++ks) b1[ks] = Bw[((size_t)8 + ks) * 64 + lane];

#pragma unroll
    for (int j = 0; j < 16; ++j) {
        if (j < 14) {
#pragma unroll
            for (int ks = 0; ks < 8; ++ks)
                b2[ks] = Bw[((size_t)(j + 2) * 8 + ks) * 64 + lane];
        }
        f32x4 acc0 = {}, acc1 = {};
#pragma unroll
        for (int ks = 0; ks < 8; ++ks) {
            acc0 = __builtin_amdgcn_mfma_f32_16x16x32_f16(afr[0][ks], b0[ks], acc0, 0, 0, 0);
            acc1 = __builtin_amdgcn_mfma_f32_16x16x32_f16(afr[1][ks], b0[ks], acc1, 0, 0, 0);
        }

        const int nt = nq * 16 + j;
        const float bs = bias[nt * 16 + l15];
#pragma unroll
        for (int rr = 0; rr < 4; ++rr) {
            const int b0i = mtp * 16 + lp * 4 + rr;
            const int b1i = b0i + 16;
            xWT[((size_t)((dir * BATCH + b0i) * TLEN + t)) * G4H + nt * 16 + l15] =
                __float2half(acc0[rr] + bs);
            xWT[((size_t)((dir * BATCH + b1i) * TLEN + t)) * G4H + nt * 16 + l15] =
                __float2half(acc1[rr] + bs);
        }
#pragma unroll
        for (int ks = 0; ks < 8; ++ks) { b0[ks] = b1[ks]; b1[ks] = b2[ks]; }
    }
}

// ---------------------------------------------------------------------------
// K2: batch-split LSTM v6 (R17/R19, unchanged) — one batch per block,
// 128 blocks. Wh int8 x256 in hard-coded AGPRs; v_mfma_i32_16x16x64_i8.
// ---------------------------------------------------------------------------

#define WBF1(SLOT, A0, A1, A2, A3)                                           \
    {                                                                        \
        const u32x4v v_ = base[(SLOT) * 64 + lane];                          \
        asm volatile("v_accvgpr_write_b32 a" A0 ", %0\n\t"                   \
                     "v_accvgpr_write_b32 a" A1 ", %1\n\t"                   \
                     "v_accvgpr_write_b32 a" A2 ", %2\n\t"                   \
                     "v_accvgpr_write_b32 a" A3 ", %3"                       \
                     :: "v"(v_[0]), "v"(v_[1]), "v"(v_[2]), "v"(v_[3])       \
                     : "a" A0, "a" A1, "a" A2, "a" A3);                      \
    }

#define MFMA1(ACC, S0, S3)                                                   \
    asm("v_mfma_i32_16x16x64_i8 %0, %1, a[" S0 ":" S3 "], %0"                \
        : "+v"(ACC) : "v"(areg))

__global__ __launch_bounds__(512, 2)
void lstm_kernel(const __half* __restrict__ xWT,
                 const u32x4v* __restrict__ WhI8,
                 __half* __restrict__ hist) {
    const int bg  = blockIdx.x;       // 0..63 (one batch)
    const int dir = blockIdx.y;       // 0..1
    const int tid = threadIdx.x;
    const int lane = tid & 63;
    const int w    = tid >> 6;        // wave 0..7
    const int l15  = lane & 15;
    const int lp   = lane >> 4;

    __shared__ signed char h8[2 * 256];   // int8(127*h), double-buffered
    __shared__ int gbuf[4 * 256];         // [gate4][u256] i32 gate accums

    const __half* xwD = xWT + (size_t)(dir * BATCH + bg) * ((size_t)TLEN * G4H);
    __half* hD = hist + (size_t)(dir * BATCH + bg) * TLEN * HSZ;

    // ---- load 32 Wh i8 B-frags into a0..a127 (slot s -> a[4s:4s+3]) ----
    {
        const u32x4v* base = WhI8 + (size_t)(dir * 8 + w) * 2048;
        WBF1( 0,  "0",  "1",  "2",  "3")  WBF1( 1,  "4",  "5",  "6",  "7")
        WBF1( 2,  "8",  "9", "10", "11")  WBF1( 3, "12", "13", "14", "15")
        WBF1( 4, "16", "17", "18", "19")  WBF1( 5, "20", "21", "22", "23")
        WBF1( 6, "24", "25", "26", "27")  WBF1( 7, "28", "29", "30", "31")
        WBF1( 8, "32", "33", "34", "35")  WBF1( 9, "36", "37", "38", "39")
        WBF1(10, "40", "41", "42", "43")  WBF1(11, "44", "45", "46", "47")
        WBF1(12, "48", "49", "50", "51")  WBF1(13, "52", "53", "54", "55")
        WBF1(14, "56", "57", "58", "59")  WBF1(15, "60", "61", "62", "63")
        WBF1(16, "64", "65", "66", "67")  WBF1(17, "68", "69", "70", "71")
        WBF1(18, "72", "73", "74", "75")  WBF1(19, "76", "77", "78", "79")
        WBF1(20, "80", "81", "82", "83")  WBF1(21, "84", "85", "86", "87")
        WBF1(22, "88", "89", "90", "91")  WBF1(23, "92", "93", "94", "95")
        WBF1(24, "96", "97", "98", "99")  WBF1(25, "100", "101", "102", "103")
        WBF1(26, "104", "105", "106", "107") WBF1(27, "108", "109", "110", "111")
        WBF1(28, "112", "113", "114", "115") WBF1(29, "116", "117", "118", "119")
        WBF1(30, "120", "121", "122", "123") WBF1(31, "124", "125", "126", "127")
        asm volatile("s_nop 7\n\ts_nop 7" :::);   // accvgpr_write -> mfma hazard
    }

    for (int i = tid; i < 128; i += 512) ((unsigned int*)h8)[i] = 0;   // zero both bufs

    float c0 = 0.0f;                  // cell state for unit tid (tid<256)
    ushort xwc[4], xwn[4];            // per-unit xW gates (tid<256)
    if (tid < 256) {
        const __half* p0 = xwD + (size_t)(dir ? (TLEN - 1) : 0) * G4H;
#pragma unroll
        for (int g = 0; g < 4; ++g)
            xwc[g] = __half_as_ushort(p0[g * 256 + tid]);
    }
    __syncthreads();   // h8 init + AGPR loads complete

    i32x4 acc[8];
    int p = 0;
    for (int ts = 0; ts < TLEN; ++ts) {
        const int t = dir ? (TLEN - 1 - ts) : ts;
        const signed char* h8r = h8 + p * 256;

#pragma unroll
        for (int gg = 0; gg < 8; ++gg) { i32x4 z = {0,0,0,0}; acc[gg] = z; }

        // recurrent matmul: h8[p] x a0..a127 -> acc (i32 exact)
#define KS_BLOCK(KS, P0a,P0b, P1a,P1b, P2a,P2b, P3a,P3b, P4a,P4b, P5a,P5b, P6a,P6b, P7a,P7b) \
        {                                                                                    \
            const u32x4v areg = *(const u32x4v*)(h8r + (KS) * 64 + lp * 16);                 \
            MFMA1(acc[0], P0a, P0b); MFMA1(acc[1], P1a, P1b);                                \
            MFMA1(acc[2], P2a, P2b); MFMA1(acc[3], P3a, P3b);                                \
            MFMA1(acc[4], P4a, P4b); MFMA1(acc[5], P5a, P5b);                                \
            MFMA1(acc[6], P6a, P6b); MFMA1(acc[7], P7a, P7b);                                \
        }
        KS_BLOCK(0,  "0","3",  "16","19", "32","35", "48","51", "64","67", "80","83", "96","99",  "112","115")
        KS_BLOCK(1,  "4","7",  "20","23", "36","39", "52","55", "68","71", "84","87", "100","103","116","119")
        KS_BLOCK(2,  "8","11", "24","27", "40","43", "56","59", "72","75", "88","91", "104","107","120","123")
        KS_BLOCK(3, "12","15", "28","31", "44","47", "60","63", "76","79", "92","95", "108","111","124","127")
#undef KS_BLOCK

        // scatter gate accs (row 0 = lanes 0-15, reg 0) to gbuf
        if (lane < 16) {
            const int ubase = w * 32 + l15;
#pragma unroll
            for (int gg = 0; gg < 8; ++gg)
                gbuf[(gg >> 1) * 256 + ubase + (gg & 1) * 16] = acc[gg][0];
        }
        ldsbar();   // B1: gbuf ready

        // full-lane cell update: 256 units over threads 0..255
        if (tid < 256) {
            const int u = tid;
            const float inv = 3.0757688e-5f;   // 1/(127*256)
            const float gi = (float)__ushort_as_half(xwc[0]) + (float)gbuf[0 * 256 + u] * inv;
            const float gf = (float)__ushort_as_half(xwc[1]) + (float)gbuf[1 * 256 + u] * inv;
            const float gz = (float)__ushort_as_half(xwc[2]) + (float)gbuf[2 * 256 + u] * inv;
            const float go = (float)__ushort_as_half(xwc[3]) + (float)gbuf[3 * 256 + u] * inv;
            const float ig = sigmoid_f(gi);
            const float fg = sigmoid_f(gf);
            const float gv = tanh_f(gz);
            const float og = sigmoid_f(go);
            c0 = fg * c0 + ig * gv;
            const float hv = og * tanh_f(c0);
            hD[(size_t)t * HSZ + u] = __float2half(hv);          // direct hist store
            h8[(p ^ 1) * 256 + u] = (signed char)__float2int_rn(hv * 127.0f);
            const int tn = dir ? (t > 0 ? t - 1 : 0) : (t < TLEN - 1 ? t + 1 : t);
            const __half* pp = xwD + (size_t)tn * G4H;
#pragma unroll
            for (int g = 0; g < 4; ++g)
                xwn[g] = __half_as_ushort(pp[g * 256 + u]);
        }
        ldsbar();   // B2: h(t) in buffer p^1 visible to all waves

        if (tid < 256) {
#pragma unroll
            for (int g = 0; g < 4; ++g) xwc[g] = xwn[g];
        }
        p ^= 1;
    }
}
#undef WBF1
#undef MFMA1

// ---------------------------------------------------------------------------
// K3: emissions em[b][t][k] = hf(b,t,:).fcW[k,0:256] + hb(b,t,:).fcW[k,256:512]
// ---------------------------------------------------------------------------
__global__ __launch_bounds__(256)
void em_kernel(const __half* __restrict__ hist, const float* __restrict__ fcW,
               float* __restrict__ em) {
    const int b   = blockIdx.x >> 3;
    const int t0  = (blockIdx.x & 7) * 64;
    const int tid = threadIdx.x;

    __shared__ ushort hf[64][264];
    __shared__ ushort hb[64][264];
    __shared__ ushort fcs[32][520];

    for (int i = tid; i < 32 * 128; i += 256) {   // 4096 float4s of fcW
        const int k = i >> 7, j4 = i & 127;
        const float4 f = *(const float4*)&fcW[(size_t)k * HID + j4 * 4];
        unsigned long long pk =
              (unsigned long long)__half_as_ushort(__float2half(f.x))
            | ((unsigned long long)__half_as_ushort(__float2half(f.y)) << 16)
            | ((unsigned long long)__half_as_ushort(__float2half(f.z)) << 32)
            | ((unsigned long long)__half_as_ushort(__float2half(f.w)) << 48);
        *(unsigned long long*)&fcs[k][j4 * 4] = pk;
    }
    const __half* hfp = hist;
    const __half* hbp = hist + (size_t)BATCH * TLEN * HSZ;
    for (int i = tid; i < 64 * 32; i += 256) {
        const int row = i >> 5, seg = i & 31;
        const uint4 vf = *(const uint4*)(hfp + ((size_t)b * TLEN + t0 + row) * HSZ + seg*8);
        const uint4 vb = *(const uint4*)(hbp + ((size_t)b * TLEN + t0 + row) * HSZ + seg*8);
        *(uint4*)&hf[row][seg*8] = vf;
        *(uint4*)&hb[row][seg*8] = vb;
    }
    __syncthreads();

    const int tok = tid >> 2;     // 0..63
    const int kq  = tid & 3;      // k = kq*8 + kk
    float s[8] = {0,0,0,0,0,0,0,0};
    for (int j2 = 0; j2 < 128; ++j2) {
        const unsigned hfv = *(const unsigned*)&hf[tok][j2*2];
        const unsigned hbv = *(const unsigned*)&hb[tok][j2*2];
#pragma unroll
        for (int kk = 0; kk < 8; ++kk) {
            const int k = kq*8 + kk;
            s[kk] = fdot2f(hfv, *(const unsigned*)&fcs[k][j2*2], s[kk]);
            s[kk] = fdot2f(hbv, *(const unsigned*)&fcs[k][256 + j2*2], s[kk]);
        }
    }
    float* dst = em + ((size_t)b * TLEN + t0 + tok) * TAGS + kq*8;
#pragma unroll
    for (int kk = 0; kk < 8; ++kk) dst[kk] = s[kk];
}

// ---------------------------------------------------------------------------
// K4: CRF forward + gold score — parallel (R18 version, measured best).
// grid 64, block 128.
// ---------------------------------------------------------------------------
__global__ __launch_bounds__(128)
void crf_kernel(const float* __restrict__ em, const float* __restrict__ fcb,
                const float* __restrict__ trans, const float* __restrict__ startv,
                const float* __restrict__ endv, const int* __restrict__ y,
                float* __restrict__ partial) {
    const int b   = blockIdx.x;
    const int tid = threadIdx.x;          // 0..127
    const int tag = tid >> 2, q = tid & 3;

    __shared__ float alpha[2][TAGS];
    __shared__ float trs[TAGS][TAGS + 1]; // trs[k2][tag]
    __shared__ float gpart[2];
    __shared__ float logZs;

    for (int i = tid; i < TAGS * TAGS; i += 128)
        trs[i >> 5][i & 31] = trans[i];

    const float* e = em + (size_t)b * TLEN * TAGS;

    if (tid < TAGS)
        alpha[0][tid] = startv[tid] + e[tid] + fcb[tid];
    __syncthreads();

    const float fcbt = fcb[tag];
    float ecur = e[TAGS + tag];           // emission for t = 1
    int p = 0;
    for (int t = 1; t < TLEN; ++t) {
        float vs[8], m = -3.0e38f;
#pragma unroll
        for (int i = 0; i < 8; ++i) {
            const float v = alpha[p][q * 8 + i] + trs[q * 8 + i][tag];
            vs[i] = v; m = fmaxf(m, v);
        }
        m = fmaxf(m, __shfl_xor(m, 1, 64));
        m = fmaxf(m, __shfl_xor(m, 2, 64));
        float s = 0.0f;
#pragma unroll
        for (int i = 0; i < 8; ++i) s += __expf(vs[i] - m);
        s += __shfl_xor(s, 1, 64);
        s += __shfl_xor(s, 2, 64);
        const int tn = (t + 1 < TLEN) ? (t + 1) : t;
        const float enext = e[(size_t)tn * TAGS + tag];
        if (q == 0) alpha[p ^ 1][tag] = m + __logf(s) + ecur + fcbt;
        __syncthreads();
        ecur = enext;
        p ^= 1;
    }

    {
        const float v = (tid < TAGS) ? (alpha[p][tid] + endv[tid]) : -3.0e38f;
        if (tid < 64) {
            float mx = v;
#pragma unroll
            for (int off = 32; off; off >>= 1) mx = fmaxf(mx, __shfl_xor(mx, off, 64));
            float ex = (tid < TAGS) ? __expf(v - mx) : 0.0f;
#pragma unroll
            for (int off = 32; off; off >>= 1) ex += __shfl_xor(ex, off, 64);
            if (tid == 0) logZs = mx + __logf(ex);
        }
    }

    const int* yb = y + (size_t)b * TLEN;
    float gsum = 0.0f;
    for (int t = tid; t < TLEN; t += 128) {
        const int yt = yb[t];
        gsum += e[t * TAGS + yt] + fcb[yt];
    }
    for (int t = tid; t < TLEN - 1; t += 128)
        gsum += trans[yb[t] * TAGS + yb[t + 1]];
#pragma unroll
    for (int off = 32; off; off >>= 1) gsum += __shfl_xor(gsum, off, 64);
    if ((tid & 63) == 0) gpart[tid >> 6] = gsum;
    __syncthreads();
    if (tid == 0) {
        const float num = startv[yb[0]] + gpart[0] + gpart[1] + endv[yb[TLEN - 1]];
        partial[b] = logZs - num;
    }
}

// ---------------------------------------------------------------------------
// K5: final mean
// ---------------------------------------------------------------------------
__global__ void reduce_kernel(const float* __restrict__ partial, float* __restrict__ out) {
    float v = partial[threadIdx.x];
#pragma unroll
    for (int off = 32; off; off >>= 1) v += __shfl_xor(v, off, 64);
    if (threadIdx.x == 0) out[0] = v * (1.0f / BATCH);
}

// ---------------------------------------------------------------------------
extern "C" void kernel_launch(void* const* d_in, const int* in_sizes, int n_in,
                              void* d_out, int out_size, void* d_ws, size_t ws_size,
                              hipStream_t stream) {
    (void)in_sizes; (void)n_in; (void)out_size; (void)ws_size;

    const int*   X      = (const int*)  d_in[0];
    const int*   y      = (const int*)  d_in[1];
    const float* embed  = (const float*)d_in[2];
    const float* Wi_f   = (const float*)d_in[3];
    const float* Wh_f   = (const float*)d_in[4];
    const float* b_f    = (const float*)d_in[5];
    const float* Wi_b   = (const float*)d_in[6];
    const float* Wh_b   = (const float*)d_in[7];
    const float* b_b    = (const float*)d_in[8];
    const float* fcW    = (const float*)d_in[9];
    const float* fcb    = (const float*)d_in[10];
    const float* trans  = (const float*)d_in[11];
    const float* startv = (const float*)d_in[12];
    const float* endv   = (const float*)d_in[13];
    float* out = (float*)d_out;

    // workspace layout (em aliases xWT: xWT is dead once lstm_kernel finishes)
    char* ws = (char*)d_ws;
    __half* xWT  = (__half*)(ws);                        // [2][64][512][1024] f16 = 134217728 B
    float*  em   = (float*) (ws);                        // alias: [64][512][32] f32 = 4194304 B
    __half* hist = (__half*)(ws + 134217728);            // [2][64][512][256] f16 = 33554432 B
    u32x4v* WhI8 = (u32x4v*)(ws + 167772160);            // i8 Wh image, 524288 B
    half8*  WiT  = (half8*) (ws + 168296448);            // f16 Wi image, 1048576 B
    float*  prt  = (float*) (ws + 169345024);            // 256 B

    prep_kernel<<<384, 256, 0, stream>>>(Wh_f, Wh_b, WhI8, Wi_f, Wi_b, WiT);

    dim3 ggrid(TLEN, 2);
    gemm_xwt_kernel<<<ggrid, 512, 0, stream>>>(X, embed, WiT, b_f, b_b, xWT);

    dim3 lgrid(BATCH, 2);
    lstm_kernel<<<lgrid, 512, 0, stream>>>(xWT, WhI8, hist);

    em_kernel<<<BATCH * 8, 256, 0, stream>>>(hist, fcW, em);

    crf_kernel<<<BATCH, 128, 0, stream>>>(em, fcb, trans, startv, endv, y, prt);

    reduce_kernel<<<1, 64, 0, stream>>>(prt, out);
}

// Round 22
// 956.849 us; speedup vs baseline: 1.0439x; 1.0439x over previous
//
#include <hip/hip_runtime.h>
#include <hip/hip_fp16.h>
#include <stdint.h>

// Problem constants (NamedEntityRecognitionModel)
#define TAGS  32
#define EMB   256
#define HID   512
#define HSZ   256        // per-direction hidden
#define G4H   1024       // 4*HSZ
#define BATCH 64
#define TLEN  512

typedef _Float16 half8  __attribute__((ext_vector_type(8)));
typedef _Float16 half2v __attribute__((ext_vector_type(2)));
typedef float    f32x4  __attribute__((ext_vector_type(4)));
typedef int      i32x4  __attribute__((ext_vector_type(4)));
typedef unsigned int u32x4v __attribute__((ext_vector_type(4)));

#if defined(__has_builtin)
#if __has_builtin(__builtin_amdgcn_fdot2)
#define HAVE_FDOT2 1
#endif
#endif

__device__ __forceinline__ float fdot2f(unsigned a, unsigned b, float c) {
    half2v ha = __builtin_bit_cast(half2v, a);
    half2v hb = __builtin_bit_cast(half2v, b);
#ifdef HAVE_FDOT2
    return __builtin_amdgcn_fdot2(ha, hb, c, false);
#else
    return c + (float)ha[0]*(float)hb[0] + (float)ha[1]*(float)hb[1];
#endif
}
__device__ __forceinline__ float sigmoid_f(float x){ return 1.0f/(1.0f+__expf(-x)); }
__device__ __forceinline__ float tanh_f(float x){ return 1.0f - 2.0f/(__expf(2.0f*x)+1.0f); }

// LDS-only barrier (R14-verified equal to __syncthreads here).
__device__ __forceinline__ void ldsbar() {
    asm volatile("s_waitcnt lgkmcnt(0)" ::: "memory");
    __builtin_amdgcn_sched_barrier(0);
    __builtin_amdgcn_s_barrier();
    __builtin_amdgcn_sched_barrier(0);
}

// ---------------------------------------------------------------------------
// K0a: int8 MFMA B-fragment image of Wh, scaled by 256.
// ---------------------------------------------------------------------------
__global__ __launch_bounds__(256)
void whimg_kernel(const float* __restrict__ WhF, const float* __restrict__ WhB,
                  u32x4v* __restrict__ WhI8) {
    const int id = blockIdx.x * 256 + threadIdx.x;   // 0..32767
    const int dir = id >> 14, r = id & 16383;
    const int lane = r & 63;
    const int ks = (r >> 6) & 3;
    const int gg = (r >> 8) & 7;
    const int w  = (r >> 11) & 7;
    const int n = (gg >> 1) * 256 + w * 32 + (gg & 1) * 16 + (lane & 15);
    const int k = ks * 64 + (lane >> 4) * 16;
    const float* src = (dir ? WhB : WhF) + (size_t)n * HSZ + k;
    u32x4v out;
#pragma unroll
    for (int d = 0; d < 4; ++d) {
        unsigned dw = 0;
#pragma unroll
        for (int e = 0; e < 4; ++e) {
            int q = __float2int_rn(src[d * 4 + e] * 256.0f);
            q = q > 127 ? 127 : (q < -127 ? -127 : q);
            dw |= ((unsigned)(q & 0xff)) << (8 * e);
        }
        out[d] = dw;
    }
    WhI8[id] = out;
}

// ---------------------------------------------------------------------------
// K0b: f16 MFMA B-fragment image of Wi (unscaled).
// ---------------------------------------------------------------------------
__global__ __launch_bounds__(256)
void wiimg_kernel(const float* __restrict__ WiF, const float* __restrict__ WiB,
                  half8* __restrict__ WiT) {
    const int slot = blockIdx.x * 256 + threadIdx.x;   // 0..65535
    const int lane = slot & 63;
    const int ks = (slot >> 6) & 7;
    const int nt = (slot >> 9) & 63;
    const int dir = slot >> 15;
    const int n = nt * 16 + (lane & 15);
    const int k = ks * 32 + (lane >> 4) * 8;
    const float* src = (dir ? WiB : WiF) + (size_t)n * EMB + k;
    half8 hv;
#pragma unroll
    for (int e = 0; e < 8; ++e) hv[e] = (_Float16)src[e];
    WiT[slot] = hv;
}

// ---------------------------------------------------------------------------
// K1: MFMA input GEMM v2 — 512 threads, wave = (mt = w&3, nhalf = w>>2).
// Each wave: ONE m-tile (afr[8] = 32 VGPR) x 32 nt tiles.
// xWT[dir][b 64][t][n 1024] f16 = embed.Wi + bias. grid (512 t, 2 dir).
// ---------------------------------------------------------------------------
__global__ __launch_bounds__(512, 2)
void gemm_xwt_kernel(const int* __restrict__ X, const float* __restrict__ embed,
                     const half8* __restrict__ WiT, const float* __restrict__ bF,
                     const float* __restrict__ bB, __half* __restrict__ xWT) {
    const int t   = blockIdx.x;
    const int dir = blockIdx.y;
    const int tid = threadIdx.x;
    const int lane = tid & 63;
    const int w    = tid >> 6;        // 0..7
    const int mt   = w & 3;           // m-tile of this wave
    const int nh   = w >> 2;          // n-half (32 nt each)
    const int l15  = lane & 15;
    const int lp   = lane >> 4;
    const float* bias = dir ? bB : bF;

    __shared__ ushort A[4 * 8 * 64 * 8];   // [mt][ks][lane][8e] f16 = 32 KB

    // ---- stage A: row b = tid>>3, k-slice ks = tid&7 (32 floats) ----
    {
        const int b = tid >> 3, ks = tid & 7;
        const int erow = X[b * TLEN + t];
        const float* src = embed + (size_t)erow * EMB + ks * 32;
        const int amt = b >> 4, bl = b & 15;
#pragma unroll
        for (int lpp = 0; lpp < 4; ++lpp) {
            const float4 x0 = *(const float4*)(src + lpp * 8);
            const float4 x1 = *(const float4*)(src + lpp * 8 + 4);
            half8 hv;
            hv[0]=(_Float16)x0.x; hv[1]=(_Float16)x0.y; hv[2]=(_Float16)x0.z; hv[3]=(_Float16)x0.w;
            hv[4]=(_Float16)x1.x; hv[5]=(_Float16)x1.y; hv[6]=(_Float16)x1.z; hv[7]=(_Float16)x1.w;
            *(half8*)&A[(((amt * 8 + ks) * 64) + lpp * 16 + bl) * 8] = hv;
        }
    }
    __syncthreads();

    // ---- hoist this wave's A-frags (one m-tile): 32 VGPR ----
    half8 afr[8];
#pragma unroll
    for (int ks = 0; ks < 8; ++ks)
        afr[ks] = *(const half8*)&A[(((mt * 8 + ks) * 64) + lane) * 8];

    const half8* Bw = WiT + (size_t)(dir * 64 + nh * 32) * 8 * 64;

    half8 bcur[8], bnxt[8];
#pragma unroll
    for (int ks = 0; ks < 8; ++ks) bcur[ks] = Bw[(size_t)ks * 64 + lane];

#pragma unroll 4
    for (int j = 0; j < 32; ++j) {
        if (j < 31) {
#pragma unroll
            for (int ks = 0; ks < 8; ++ks)
                bnxt[ks] = Bw[((size_t)(j + 1) * 8 + ks) * 64 + lane];
        }
        f32x4 acc4 = {};
#pragma unroll
        for (int ks = 0; ks < 8; ++ks)
            acc4 = __builtin_amdgcn_mfma_f32_16x16x32_f16(afr[ks], bcur[ks], acc4, 0, 0, 0);

        const int nt = nh * 32 + j;
        const float bs = bias[nt * 16 + l15];
#pragma unroll
        for (int rr = 0; rr < 4; ++rr) {
            const int b = mt * 16 + lp * 4 + rr;
            const __half hh = __float2half(acc4[rr] + bs);
            xWT[((size_t)((dir * BATCH + b) * TLEN + t)) * G4H + nt * 16 + l15] = hh;
        }
#pragma unroll
        for (int ks = 0; ks < 8; ++ks) bcur[ks] = bnxt[ks];
    }
}

// ---------------------------------------------------------------------------
// K2: batch-split LSTM v6 (R17, unchanged) — one batch per block, 128 blocks.
// Wh int8 x256 in hard-coded AGPRs; v_mfma_i32_16x16x64_i8; exact i32 accum.
// ---------------------------------------------------------------------------

#define WBF1(SLOT, A0, A1, A2, A3)                                           \
    {                                                                        \
        const u32x4v v_ = base[(SLOT) * 64 + lane];                          \
        asm volatile("v_accvgpr_write_b32 a" A0 ", %0\n\t"                   \
                     "v_accvgpr_write_b32 a" A1 ", %1\n\t"                   \
                     "v_accvgpr_write_b32 a" A2 ", %2\n\t"                   \
                     "v_accvgpr_write_b32 a" A3 ", %3"                       \
                     :: "v"(v_[0]), "v"(v_[1]), "v"(v_[2]), "v"(v_[3])       \
                     : "a" A0, "a" A1, "a" A2, "a" A3);                      \
    }

#define MFMA1(ACC, S0, S3)                                                   \
    asm("v_mfma_i32_16x16x64_i8 %0, %1, a[" S0 ":" S3 "], %0"                \
        : "+v"(ACC) : "v"(areg))

__global__ __launch_bounds__(512, 2)
void lstm_kernel(const __half* __restrict__ xWT,
                 const u32x4v* __restrict__ WhI8,
                 __half* __restrict__ hist) {
    const int bg  = blockIdx.x;       // 0..63 (one batch)
    const int dir = blockIdx.y;       // 0..1
    const int tid = threadIdx.x;
    const int lane = tid & 63;
    const int w    = tid >> 6;        // wave 0..7
    const int l15  = lane & 15;
    const int lp   = lane >> 4;

    __shared__ signed char h8[2 * 256];   // int8(127*h), double-buffered
    __shared__ int gbuf[4 * 256];         // [gate4][u256] i32 gate accums

    const __half* xwD = xWT + (size_t)(dir * BATCH + bg) * ((size_t)TLEN * G4H);
    __half* hD = hist + (size_t)(dir * BATCH + bg) * TLEN * HSZ;

    // ---- load 32 Wh i8 B-frags into a0..a127 (slot s -> a[4s:4s+3]) ----
    {
        const u32x4v* base = WhI8 + (size_t)(dir * 8 + w) * 2048;
        WBF1( 0,  "0",  "1",  "2",  "3")  WBF1( 1,  "4",  "5",  "6",  "7")
        WBF1( 2,  "8",  "9", "10", "11")  WBF1( 3, "12", "13", "14", "15")
        WBF1( 4, "16", "17", "18", "19")  WBF1( 5, "20", "21", "22", "23")
        WBF1( 6, "24", "25", "26", "27")  WBF1( 7, "28", "29", "30", "31")
        WBF1( 8, "32", "33", "34", "35")  WBF1( 9, "36", "37", "38", "39")
        WBF1(10, "40", "41", "42", "43")  WBF1(11, "44", "45", "46", "47")
        WBF1(12, "48", "49", "50", "51")  WBF1(13, "52", "53", "54", "55")
        WBF1(14, "56", "57", "58", "59")  WBF1(15, "60", "61", "62", "63")
        WBF1(16, "64", "65", "66", "67")  WBF1(17, "68", "69", "70", "71")
        WBF1(18, "72", "73", "74", "75")  WBF1(19, "76", "77", "78", "79")
        WBF1(20, "80", "81", "82", "83")  WBF1(21, "84", "85", "86", "87")
        WBF1(22, "88", "89", "90", "91")  WBF1(23, "92", "93", "94", "95")
        WBF1(24, "96", "97", "98", "99")  WBF1(25, "100", "101", "102", "103")
        WBF1(26, "104", "105", "106", "107") WBF1(27, "108", "109", "110", "111")
        WBF1(28, "112", "113", "114", "115") WBF1(29, "116", "117", "118", "119")
        WBF1(30, "120", "121", "122", "123") WBF1(31, "124", "125", "126", "127")
        asm volatile("s_nop 7\n\ts_nop 7" :::);   // accvgpr_write -> mfma hazard
    }

    for (int i = tid; i < 128; i += 512) ((unsigned int*)h8)[i] = 0;   // zero both bufs

    float c0 = 0.0f;                  // cell state for unit tid (tid<256)
    ushort xwc[4], xwn[4];            // per-unit xW gates (tid<256)
    if (tid < 256) {
        const __half* p0 = xwD + (size_t)(dir ? (TLEN - 1) : 0) * G4H;
#pragma unroll
        for (int g = 0; g < 4; ++g)
            xwc[g] = __half_as_ushort(p0[g * 256 + tid]);
    }
    __syncthreads();   // h8 init + AGPR loads complete

    i32x4 acc[8];
    int p = 0;
    for (int ts = 0; ts < TLEN; ++ts) {
        const int t = dir ? (TLEN - 1 - ts) : ts;
        const signed char* h8r = h8 + p * 256;

#pragma unroll
        for (int gg = 0; gg < 8; ++gg) { i32x4 z = {0,0,0,0}; acc[gg] = z; }

        // recurrent matmul: h8[p] x a0..a127 -> acc (i32 exact)
#define KS_BLOCK(KS, P0a,P0b, P1a,P1b, P2a,P2b, P3a,P3b, P4a,P4b, P5a,P5b, P6a,P6b, P7a,P7b) \
        {                                                                                    \
            const u32x4v areg = *(const u32x4v*)(h8r + (KS) * 64 + lp * 16);                 \
            MFMA1(acc[0], P0a, P0b); MFMA1(acc[1], P1a, P1b);                                \
            MFMA1(acc[2], P2a, P2b); MFMA1(acc[3], P3a, P3b);                                \
            MFMA1(acc[4], P4a, P4b); MFMA1(acc[5], P5a, P5b);                                \
            MFMA1(acc[6], P6a, P6b); MFMA1(acc[7], P7a, P7b);                                \
        }
        KS_BLOCK(0,  "0","3",  "16","19", "32","35", "48","51", "64","67", "80","83", "96","99",  "112","115")
        KS_BLOCK(1,  "4","7",  "20","23", "36","39", "52","55", "68","71", "84","87", "100","103","116","119")
        KS_BLOCK(2,  "8","11", "24","27", "40","43", "56","59", "72","75", "88","91", "104","107","120","123")
        KS_BLOCK(3, "12","15", "28","31", "44","47", "60","63", "76","79", "92","95", "108","111","124","127")
#undef KS_BLOCK

        // scatter gate accs (row 0 = lanes 0-15, reg 0) to gbuf
        if (lane < 16) {
            const int ubase = w * 32 + l15;
#pragma unroll
            for (int gg = 0; gg < 8; ++gg)
                gbuf[(gg >> 1) * 256 + ubase + (gg & 1) * 16] = acc[gg][0];
        }
        ldsbar();   // B1: gbuf ready

        // full-lane cell update: 256 units over threads 0..255
        if (tid < 256) {
            const int u = tid;
            const float inv = 3.0757688e-5f;   // 1/(127*256)
            const float gi = (float)__ushort_as_half(xwc[0]) + (float)gbuf[0 * 256 + u] * inv;
            const float gf = (float)__ushort_as_half(xwc[1]) + (float)gbuf[1 * 256 + u] * inv;
            const float gz = (float)__ushort_as_half(xwc[2]) + (float)gbuf[2 * 256 + u] * inv;
            const float go = (float)__ushort_as_half(xwc[3]) + (float)gbuf[3 * 256 + u] * inv;
            const float ig = sigmoid_f(gi);
            const float fg = sigmoid_f(gf);
            const float gv = tanh_f(gz);
            const float og = sigmoid_f(go);
            c0 = fg * c0 + ig * gv;
            const float hv = og * tanh_f(c0);
            hD[(size_t)t * HSZ + u] = __float2half(hv);          // direct hist store
            h8[(p ^ 1) * 256 + u] = (signed char)__float2int_rn(hv * 127.0f);
            const int tn = dir ? (t > 0 ? t - 1 : 0) : (t < TLEN - 1 ? t + 1 : t);
            const __half* pp = xwD + (size_t)tn * G4H;
#pragma unroll
            for (int g = 0; g < 4; ++g)
                xwn[g] = __half_as_ushort(pp[g * 256 + u]);
        }
        ldsbar();   // B2: h(t) in buffer p^1 visible to all waves

        if (tid < 256) {
#pragma unroll
            for (int g = 0; g < 4; ++g) xwc[g] = xwn[g];
        }
        p ^= 1;
    }
}
#undef WBF1
#undef MFMA1

// ---------------------------------------------------------------------------
// K3: emissions em[b][t][k] = hf(b,t,:).fcW[k,0:256] + hb(b,t,:).fcW[k,256:512]
// ---------------------------------------------------------------------------
__global__ __launch_bounds__(256)
void em_kernel(const __half* __restrict__ hist, const float* __restrict__ fcW,
               float* __restrict__ em) {
    const int b   = blockIdx.x >> 3;
    const int t0  = (blockIdx.x & 7) * 64;
    const int tid = threadIdx.x;

    __shared__ ushort hf[64][264];
    __shared__ ushort hb[64][264];
    __shared__ ushort fcs[32][520];

    for (int i = tid; i < 32 * 128; i += 256) {   // 4096 float4s of fcW
        const int k = i >> 7, j4 = i & 127;
        const float4 f = *(const float4*)&fcW[(size_t)k * HID + j4 * 4];
        unsigned long long pk =
              (unsigned long long)__half_as_ushort(__float2half(f.x))
            | ((unsigned long long)__half_as_ushort(__float2half(f.y)) << 16)
            | ((unsigned long long)__half_as_ushort(__float2half(f.z)) << 32)
            | ((unsigned long long)__half_as_ushort(__float2half(f.w)) << 48);
        *(unsigned long long*)&fcs[k][j4 * 4] = pk;
    }
    const __half* hfp = hist;
    const __half* hbp = hist + (size_t)BATCH * TLEN * HSZ;
    for (int i = tid; i < 64 * 32; i += 256) {
        const int row = i >> 5, seg = i & 31;
        const uint4 vf = *(const uint4*)(hfp + ((size_t)b * TLEN + t0 + row) * HSZ + seg*8);
        const uint4 vb = *(const uint4*)(hbp + ((size_t)b * TLEN + t0 + row) * HSZ + seg*8);
        *(uint4*)&hf[row][seg*8] = vf;
        *(uint4*)&hb[row][seg*8] = vb;
    }
    __syncthreads();

    const int tok = tid >> 2;     // 0..63
    const int kq  = tid & 3;      // k = kq*8 + kk
    float s[8] = {0,0,0,0,0,0,0,0};
    for (int j2 = 0; j2 < 128; ++j2) {
        const unsigned hfv = *(const unsigned*)&hf[tok][j2*2];
        const unsigned hbv = *(const unsigned*)&hb[tok][j2*2];
#pragma unroll
        for (int kk = 0; kk < 8; ++kk) {
            const int k = kq*8 + kk;
            s[kk] = fdot2f(hfv, *(const unsigned*)&fcs[k][j2*2], s[kk]);
            s[kk] = fdot2f(hbv, *(const unsigned*)&fcs[k][256 + j2*2], s[kk]);
        }
    }
    float* dst = em + ((size_t)b * TLEN + t0 + tok) * TAGS + kq*8;
#pragma unroll
    for (int kk = 0; kk < 8; ++kk) dst[kk] = s[kk];
}

// ---------------------------------------------------------------------------
// K4: CRF forward + gold score — parallel (R18, measured best). grid 64, block 128.
// ---------------------------------------------------------------------------
__global__ __launch_bounds__(128)
void crf_kernel(const float* __restrict__ em, const float* __restrict__ fcb,
                const float* __restrict__ trans, const float* __restrict__ startv,
                const float* __restrict__ endv, const int* __restrict__ y,
                float* __restrict__ partial) {
    const int b   = blockIdx.x;
    const int tid = threadIdx.x;          // 0..127
    const int tag = tid >> 2, q = tid & 3;

    __shared__ float alpha[2][TAGS];
    __shared__ float trs[TAGS][TAGS + 1]; // trs[k2][tag]
    __shared__ float gpart[2];
    __shared__ float logZs;

    for (int i = tid; i < TAGS * TAGS; i += 128)
        trs[i >> 5][i & 31] = trans[i];

    const float* e = em + (size_t)b * TLEN * TAGS;

    if (tid < TAGS)
        alpha[0][tid] = startv[tid] + e[tid] + fcb[tid];
    __syncthreads();

    const float fcbt = fcb[tag];
    float ecur = e[TAGS + tag];           // emission for t = 1
    int p = 0;
    for (int t = 1; t < TLEN; ++t) {
        float vs[8], m = -3.0e38f;
#pragma unroll
        for (int i = 0; i < 8; ++i) {
            const float v = alpha[p][q * 8 + i] + trs[q * 8 + i][tag];
            vs[i] = v; m = fmaxf(m, v);
        }
        m = fmaxf(m, __shfl_xor(m, 1, 64));
        m = fmaxf(m, __shfl_xor(m, 2, 64));
        float s = 0.0f;
#pragma unroll
        for (int i = 0; i < 8; ++i) s += __expf(vs[i] - m);
        s += __shfl_xor(s, 1, 64);
        s += __shfl_xor(s, 2, 64);
        const int tn = (t + 1 < TLEN) ? (t + 1) : t;
        const float enext = e[(size_t)tn * TAGS + tag];
        if (q == 0) alpha[p ^ 1][tag] = m + __logf(s) + ecur + fcbt;
        __syncthreads();
        ecur = enext;
        p ^= 1;
    }

    {
        const float v = (tid < TAGS) ? (alpha[p][tid] + endv[tid]) : -3.0e38f;
        if (tid < 64) {
            float mx = v;
#pragma unroll
            for (int off = 32; off; off >>= 1) mx = fmaxf(mx, __shfl_xor(mx, off, 64));
            float ex = (tid < TAGS) ? __expf(v - mx) : 0.0f;
#pragma unroll
            for (int off = 32; off; off >>= 1) ex += __shfl_xor(ex, off, 64);
            if (tid == 0) logZs = mx + __logf(ex);
        }
    }

    const int* yb = y + (size_t)b * TLEN;
    float gsum = 0.0f;
    for (int t = tid; t < TLEN; t += 128) {
        const int yt = yb[t];
        gsum += e[t * TAGS + yt] + fcb[yt];
    }
    for (int t = tid; t < TLEN - 1; t += 128)
        gsum += trans[yb[t] * TAGS + yb[t + 1]];
#pragma unroll
    for (int off = 32; off; off >>= 1) gsum += __shfl_xor(gsum, off, 64);
    if ((tid & 63) == 0) gpart[tid >> 6] = gsum;
    __syncthreads();
    if (tid == 0) {
        const float num = startv[yb[0]] + gpart[0] + gpart[1] + endv[yb[TLEN - 1]];
        partial[b] = logZs - num;
    }
}

// ---------------------------------------------------------------------------
// K5: final mean
// ---------------------------------------------------------------------------
__global__ void reduce_kernel(const float* __restrict__ partial, float* __restrict__ out) {
    float v = partial[threadIdx.x];
#pragma unroll
    for (int off = 32; off; off >>= 1) v += __shfl_xor(v, off, 64);
    if (threadIdx.x == 0) out[0] = v * (1.0f / BATCH);
}

// ---------------------------------------------------------------------------
extern "C" void kernel_launch(void* const* d_in, const int* in_sizes, int n_in,
                              void* d_out, int out_size, void* d_ws, size_t ws_size,
                              hipStream_t stream) {
    (void)in_sizes; (void)n_in; (void)out_size; (void)ws_size;

    const int*   X      = (const int*)  d_in[0];
    const int*   y      = (const int*)  d_in[1];
    const float* embed  = (const float*)d_in[2];
    const float* Wi_f   = (const float*)d_in[3];
    const float* Wh_f   = (const float*)d_in[4];
    const float* b_f    = (const float*)d_in[5];
    const float* Wi_b   = (const float*)d_in[6];
    const float* Wh_b   = (const float*)d_in[7];
    const float* b_b    = (const float*)d_in[8];
    const float* fcW    = (const float*)d_in[9];
    const float* fcb    = (const float*)d_in[10];
    const float* trans  = (const float*)d_in[11];
    const float* startv = (const float*)d_in[12];
    const float* endv   = (const float*)d_in[13];
    float* out = (float*)d_out;

    // workspace layout (em aliases xWT: xWT is dead once lstm_kernel finishes)
    char* ws = (char*)d_ws;
    __half* xWT  = (__half*)(ws);                        // [2][64][512][1024] f16 = 134217728 B
    float*  em   = (float*) (ws);                        // alias: [64][512][32] f32 = 4194304 B
    __half* hist = (__half*)(ws + 134217728);            // [2][64][512][256] f16 = 33554432 B
    u32x4v* WhI8 = (u32x4v*)(ws + 167772160);            // i8 Wh image, 524288 B
    half8*  WiT  = (half8*) (ws + 168296448);            // f16 Wi image, 1048576 B
    float*  prt  = (float*) (ws + 169345024);            // 256 B

    whimg_kernel<<<128, 256, 0, stream>>>(Wh_f, Wh_b, WhI8);
    wiimg_kernel<<<256, 256, 0, stream>>>(Wi_f, Wi_b, WiT);

    dim3 ggrid(TLEN, 2);
    gemm_xwt_kernel<<<ggrid, 512, 0, stream>>>(X, embed, WiT, b_f, b_b, xWT);

    dim3 lgrid(BATCH, 2);
    lstm_kernel<<<lgrid, 512, 0, stream>>>(xWT, WhI8, hist);

    em_kernel<<<BATCH * 8, 256, 0, stream>>>(hist, fcW, em);

    crf_kernel<<<BATCH, 128, 0, stream>>>(em, fcb, trans, startv, endv, y, prt);

    reduce_kernel<<<1, 64, 0, stream>>>(prt, out);
}